// Round 1
// baseline (1141.617 us; speedup 1.0000x reference)
//
#include <hip/hip_runtime.h>

#define C 128
#define NN 50000     // N_USER == N_ITEM
#define NE 600000
#define LN_EPS 1e-5f

// ---------------- CSR build (edges are layer-invariant; built once per call) ----------------
__global__ void count_kernel(int* __restrict__ cnt, const int* __restrict__ dst, int E) {
  int e = blockIdx.x * 256 + threadIdx.x;
  if (e < E) atomicAdd(&cnt[dst[e]], 1);
}

// one block per edge type; exclusive prefix sum over N counts -> off[0..N]
__global__ void scan3_kernel(const int* c0, int* o0, const int* c1, int* o1,
                             const int* c2, int* o2, int N) {
  const int* cnt = (blockIdx.x == 0) ? c0 : (blockIdx.x == 1) ? c1 : c2;
  int* off = (blockIdx.x == 0) ? o0 : (blockIdx.x == 1) ? o1 : o2;
  __shared__ int wsums[16];
  int tid = threadIdx.x, lane = tid & 63, wid = tid >> 6;
  if (tid == 0) off[0] = 0;
  int carry = 0;
  for (int base = 0; base < N; base += 1024) {
    int i = base + tid;
    int v = (i < N) ? cnt[i] : 0;
    int incl = v;
    #pragma unroll
    for (int d = 1; d < 64; d <<= 1) {
      int t = __shfl_up(incl, d, 64);
      if (lane >= d) incl += t;
    }
    if (lane == 63) wsums[wid] = incl;
    __syncthreads();
    if (wid == 0) {
      int w = (lane < 16) ? wsums[lane] : 0;
      #pragma unroll
      for (int d = 1; d < 16; d <<= 1) {
        int t = __shfl_up(w, d, 64);
        if (lane >= d) w += t;
      }
      if (lane < 16) wsums[lane] = w;
    }
    __syncthreads();
    int wave_prefix = (wid > 0) ? wsums[wid - 1] : 0;
    int total = wsums[15];
    if (i < N) off[i + 1] = carry + wave_prefix + incl;
    carry += total;
    __syncthreads();
  }
}

__global__ void scatter_kernel(int* __restrict__ srcs, int* __restrict__ fill,
                               const int* __restrict__ src, const int* __restrict__ dst,
                               const int* __restrict__ off, int E) {
  int e = blockIdx.x * 256 + threadIdx.x;
  if (e < E) {
    int d = dst[e];
    int pos = off[d] + atomicAdd(&fill[d], 1);
    srcs[pos] = src[e];
  }
}

// ---------------- mean aggregation: one wave per dst node ----------------
__global__ __launch_bounds__(256) void aggregate_mean_kernel(
    float* __restrict__ mean, const float* __restrict__ xsrc,
    const int* __restrict__ srcs, const int* __restrict__ off, int Ndst) {
  int wid = threadIdx.x >> 6, lane = threadIdx.x & 63;
  int n = blockIdx.x * 4 + wid;
  if (n >= Ndst) return;
  int beg = off[n], end = off[n + 1];
  float sx = 0.f, sy = 0.f;
  int e = beg;
  for (; e + 1 < end; e += 2) {   // unroll x2: two independent gathers in flight
    int s0 = srcs[e], s1 = srcs[e + 1];
    float2 v0 = *(const float2*)&xsrc[(size_t)s0 * C + lane * 2];
    float2 v1 = *(const float2*)&xsrc[(size_t)s1 * C + lane * 2];
    sx += v0.x + v1.x;
    sy += v0.y + v1.y;
  }
  if (e < end) {
    int s0 = srcs[e];
    float2 v0 = *(const float2*)&xsrc[(size_t)s0 * C + lane * 2];
    sx += v0.x;
    sy += v0.y;
  }
  float inv = 1.0f / fmaxf((float)(end - beg), 1.0f);
  *(float2*)&mean[(size_t)n * C + lane * 2] = make_float2(sx * inv, sy * inv);
}

// ---------------- Y[n][c] (+)= sum_k X[n][k]*W[c][k] (+ bias[c]) ----------------
// block: 256 thr -> 64 rows x 128 cols tile; thread: 4 rows x 8 cols
__global__ __launch_bounds__(256) void linear_kernel(
    float* __restrict__ Y, const float* __restrict__ X,
    const float* __restrict__ W, const float* __restrict__ bias,
    int N, int accum) {
  __shared__ float Xs[64][36];       // +4 pad, keeps float4 alignment
  __shared__ float Wt[32][C + 4];    // transposed W chunk: Wt[k][c]
  int tid = threadIdx.x;
  int n0 = blockIdx.x * 64;
  int tx = tid & 15;   // 16 col groups of 8
  int ty = tid >> 4;   // 16 row groups of 4
  float acc[4][8];
  #pragma unroll
  for (int i = 0; i < 4; i++)
    #pragma unroll
    for (int j = 0; j < 8; j++) acc[i][j] = 0.f;

  for (int kc = 0; kc < C; kc += 32) {
    __syncthreads();
    #pragma unroll
    for (int idx = tid; idx < 64 * 8; idx += 256) {   // 2 iters
      int r = idx >> 3, q = idx & 7;
      int gr = n0 + r;
      float4 v = make_float4(0.f, 0.f, 0.f, 0.f);
      if (gr < N) v = *(const float4*)&X[(size_t)gr * C + kc + q * 4];
      *(float4*)&Xs[r][q * 4] = v;
    }
    #pragma unroll
    for (int idx = tid; idx < 128 * 8; idx += 256) {  // 4 iters, transpose W into LDS
      int c = idx >> 3, q = idx & 7;
      float4 v = *(const float4*)&W[(size_t)c * C + kc + q * 4];
      Wt[q * 4 + 0][c] = v.x;
      Wt[q * 4 + 1][c] = v.y;
      Wt[q * 4 + 2][c] = v.z;
      Wt[q * 4 + 3][c] = v.w;
    }
    __syncthreads();
    #pragma unroll
    for (int k = 0; k < 32; k++) {
      float xr[4];
      #pragma unroll
      for (int i = 0; i < 4; i++) xr[i] = Xs[ty * 4 + i][k];
      float4 w0 = *(const float4*)&Wt[k][tx * 8];
      float4 w1 = *(const float4*)&Wt[k][tx * 8 + 4];
      #pragma unroll
      for (int i = 0; i < 4; i++) {
        acc[i][0] += xr[i] * w0.x;
        acc[i][1] += xr[i] * w0.y;
        acc[i][2] += xr[i] * w0.z;
        acc[i][3] += xr[i] * w0.w;
        acc[i][4] += xr[i] * w1.x;
        acc[i][5] += xr[i] * w1.y;
        acc[i][6] += xr[i] * w1.z;
        acc[i][7] += xr[i] * w1.w;
      }
    }
  }
  #pragma unroll
  for (int i = 0; i < 4; i++) {
    int gr = n0 + ty * 4 + i;
    if (gr >= N) continue;
    float* yp = &Y[(size_t)gr * C + tx * 8];
    float4 a0 = make_float4(acc[i][0], acc[i][1], acc[i][2], acc[i][3]);
    float4 a1 = make_float4(acc[i][4], acc[i][5], acc[i][6], acc[i][7]);
    if (bias) {
      float4 b0 = *(const float4*)&bias[tx * 8];
      float4 b1 = *(const float4*)&bias[tx * 8 + 4];
      a0.x += b0.x; a0.y += b0.y; a0.z += b0.z; a0.w += b0.w;
      a1.x += b1.x; a1.y += b1.y; a1.z += b1.z; a1.w += b1.w;
    }
    if (accum) {
      float4 o0 = *(const float4*)&yp[0];
      float4 o1 = *(const float4*)&yp[4];
      a0.x += o0.x; a0.y += o0.y; a0.z += o0.z; a0.w += o0.w;
      a1.x += o1.x; a1.y += o1.y; a1.z += o1.z; a1.w += o1.w;
    }
    *(float4*)&yp[0] = a0;
    *(float4*)&yp[4] = a1;
  }
}

// ---------------- LayerNorm (per node over C) + ReLU, in place ----------------
__global__ __launch_bounds__(256) void ln_relu_kernel(
    float* __restrict__ X, const float* __restrict__ w, const float* __restrict__ b, int N) {
  int wid = threadIdx.x >> 6, lane = threadIdx.x & 63;
  int n = blockIdx.x * 4 + wid;
  if (n >= N) return;
  int c = lane * 2;
  float2 v = *(float2*)&X[(size_t)n * C + c];
  float s = v.x + v.y;
  #pragma unroll
  for (int d = 32; d > 0; d >>= 1) s += __shfl_xor(s, d, 64);
  float mu = s * (1.0f / 128.0f);
  float cx = v.x - mu, cy = v.y - mu;
  float q = cx * cx + cy * cy;
  #pragma unroll
  for (int d = 32; d > 0; d >>= 1) q += __shfl_xor(q, d, 64);
  float r = rsqrtf(q * (1.0f / 128.0f) + LN_EPS);
  float y0 = cx * r * w[c] + b[c];
  float y1 = cy * r * w[c + 1] + b[c + 1];
  *(float2*)&X[(size_t)n * C + c] = make_float2(fmaxf(y0, 0.f), fmaxf(y1, 0.f));
}

extern "C" void kernel_launch(void* const* d_in, const int* in_sizes, int n_in,
                              void* d_out, int out_size, void* d_ws, size_t ws_size,
                              hipStream_t stream) {
  const float* xu = (const float*)d_in[0];
  const float* xi = (const float*)d_in[1];
  const int* ei[3] = { (const int*)d_in[2], (const int*)d_in[3], (const int*)d_in[4] };
  // edge type order: 0 = ui (user->item), 1 = iu (item->user), 2 = uu (user->user)

  // ---- workspace layout (~86 MB) ----
  char* p = (char*)d_ws;
  auto alloc = [&](size_t bytes) { char* r = p; p += (bytes + 255) & ~(size_t)255; return r; };
  int* cnt[3]; int* off[3]; int* srcs[3];
  for (int t = 0; t < 3; t++) {
    cnt[t]  = (int*)alloc((size_t)NN * 4);
    off[t]  = (int*)alloc((size_t)(NN + 1) * 4);
    srcs[t] = (int*)alloc((size_t)NE * 4);
  }
  float* meanb = (float*)alloc((size_t)NN * C * 4);
  float* pre_u = (float*)alloc((size_t)NN * C * 4);
  float* pre_i = (float*)alloc((size_t)NN * C * 4);

  const int EB = (NE + 255) / 256;
  for (int t = 0; t < 3; t++) hipMemsetAsync(cnt[t], 0, (size_t)NN * 4, stream);
  for (int t = 0; t < 3; t++)
    count_kernel<<<EB, 256, 0, stream>>>(cnt[t], ei[t] + NE, NE);
  scan3_kernel<<<3, 1024, 0, stream>>>(cnt[0], off[0], cnt[1], off[1], cnt[2], off[2], NN);
  for (int t = 0; t < 3; t++) hipMemsetAsync(cnt[t], 0, (size_t)NN * 4, stream);
  for (int t = 0; t < 3; t++)
    scatter_kernel<<<EB, 256, 0, stream>>>(srcs[t], cnt[t], ei[t], ei[t] + NE, off[t], NE);

  const int NB_AGG = (NN + 3) / 4;
  const int NB_LIN = (NN + 63) / 64;

  // params: 5 + 13*l: [0]=Wl_ui [1]=b_ui [2]=Wr_ui [3]=Wl_iu [4]=b_iu [5]=Wr_iu
  //                   [6]=Wl_uu [7]=b_uu [8]=Wr_uu [9]=lnw_u [10]=lnb_u [11]=lnw_i [12]=lnb_i
  const float* P[26];
  for (int k = 0; k < 26; k++) P[k] = (const float*)d_in[5 + k];

  const float* in_u = xu;
  const float* in_i = xi;
  for (int l = 0; l < 2; l++) {
    const float* const* Q = P + 13 * l;
    float* ou = (l == 0) ? pre_u : (float*)d_out;
    float* oi = (l == 0) ? pre_i : (float*)d_out + (size_t)NN * C;

    // item side: sage over ui
    aggregate_mean_kernel<<<NB_AGG, 256, 0, stream>>>(meanb, in_u, srcs[0], off[0], NN);
    linear_kernel<<<NB_LIN, 256, 0, stream>>>(oi, meanb, Q[0], Q[1], NN, 0);
    linear_kernel<<<NB_LIN, 256, 0, stream>>>(oi, in_i, Q[2], nullptr, NN, 1);
    // user side: sage over iu
    aggregate_mean_kernel<<<NB_AGG, 256, 0, stream>>>(meanb, in_i, srcs[1], off[1], NN);
    linear_kernel<<<NB_LIN, 256, 0, stream>>>(ou, meanb, Q[3], Q[4], NN, 0);
    linear_kernel<<<NB_LIN, 256, 0, stream>>>(ou, in_u, Q[5], nullptr, NN, 1);
    // user side: sage over uu (HeteroConv sum)
    aggregate_mean_kernel<<<NB_AGG, 256, 0, stream>>>(meanb, in_u, srcs[2], off[2], NN);
    linear_kernel<<<NB_LIN, 256, 0, stream>>>(ou, meanb, Q[6], Q[7], NN, 1);
    linear_kernel<<<NB_LIN, 256, 0, stream>>>(ou, in_u, Q[8], nullptr, NN, 1);
    // LN + ReLU (in place)
    ln_relu_kernel<<<NB_AGG, 256, 0, stream>>>(ou, Q[9], Q[10], NN);
    ln_relu_kernel<<<NB_AGG, 256, 0, stream>>>(oi, Q[11], Q[12], NN);

    in_u = ou;
    in_i = oi;
  }
  (void)in_sizes; (void)n_in; (void)out_size; (void)ws_size;
}

// Round 2
// 766.789 us; speedup vs baseline: 1.4888x; 1.4888x over previous
//
#include <hip/hip_runtime.h>

#define C 128
#define NN 50000     // N_USER == N_ITEM
#define NP 50048     // padded to multiple of 64 rows for GEMM tiles
#define NE 600000
#define LN_EPS 1e-5f

typedef __attribute__((ext_vector_type(8))) short short8;
typedef __attribute__((ext_vector_type(4))) float f32x4;

__device__ inline float lo16f(unsigned v) { union { unsigned i; float f; } x; x.i = v << 16; return x.f; }
__device__ inline float hi16f(unsigned v) { union { unsigned i; float f; } x; x.i = v & 0xffff0000u; return x.f; }
__device__ inline unsigned short f2bf(float f) {
  union { float f; unsigned i; } x; x.f = f;
  unsigned r = (x.i + 0x7fffu + ((x.i >> 16) & 1u)) >> 16;   // RNE
  return (unsigned short)r;
}

// ---------------- CSR build ----------------
__global__ void count_kernel(int* __restrict__ cnt, const int* __restrict__ dst, int E) {
  int e = blockIdx.x * 256 + threadIdx.x;
  if (e < E) atomicAdd(&cnt[dst[e]], 1);
}

__global__ void scan3_kernel(const int* c0, int* o0, const int* c1, int* o1,
                             const int* c2, int* o2, int N) {
  const int* cnt = (blockIdx.x == 0) ? c0 : (blockIdx.x == 1) ? c1 : c2;
  int* off = (blockIdx.x == 0) ? o0 : (blockIdx.x == 1) ? o1 : o2;
  __shared__ int wsums[16];
  int tid = threadIdx.x, lane = tid & 63, wid = tid >> 6;
  if (tid == 0) off[0] = 0;
  int carry = 0;
  for (int base = 0; base < N; base += 1024) {
    int i = base + tid;
    int v = (i < N) ? cnt[i] : 0;
    int incl = v;
    #pragma unroll
    for (int d = 1; d < 64; d <<= 1) {
      int t = __shfl_up(incl, d, 64);
      if (lane >= d) incl += t;
    }
    if (lane == 63) wsums[wid] = incl;
    __syncthreads();
    if (wid == 0) {
      int w = (lane < 16) ? wsums[lane] : 0;
      #pragma unroll
      for (int d = 1; d < 16; d <<= 1) {
        int t = __shfl_up(w, d, 64);
        if (lane >= d) w += t;
      }
      if (lane < 16) wsums[lane] = w;
    }
    __syncthreads();
    int wave_prefix = (wid > 0) ? wsums[wid - 1] : 0;
    int total = wsums[15];
    if (i < N) off[i + 1] = carry + wave_prefix + incl;
    carry += total;
    __syncthreads();
  }
}

__global__ void scatter_kernel(int* __restrict__ srcs, int* __restrict__ fill,
                               const int* __restrict__ src, const int* __restrict__ dst,
                               const int* __restrict__ off, int E) {
  int e = blockIdx.x * 256 + threadIdx.x;
  if (e < E) {
    int d = dst[e];
    int pos = off[d] + atomicAdd(&fill[d], 1);
    srcs[pos] = src[e];
  }
}

// ---------------- fp32 -> bf16 convert ----------------
__global__ void f2bf4_kernel(unsigned short* __restrict__ dst, const float* __restrict__ src, int n4) {
  int i = blockIdx.x * 256 + threadIdx.x;
  if (i >= n4) return;
  float4 v = ((const float4*)src)[i];
  ushort4 o = make_ushort4(f2bf(v.x), f2bf(v.y), f2bf(v.z), f2bf(v.w));
  ((ushort4*)dst)[i] = o;
}

// ---------------- weight pack: concat + bf16 (per layer) ----------------
// Wu[c][k]: k<128 -> Wl_iu; 128..255 -> Wr_iu+Wr_uu; 256..383 -> Wl_uu  (Ktot=384)
// Wi[c][k]: k<128 -> Wl_ui; 128..255 -> Wr_ui                           (Ktot=256)
// bu = b_iu + b_uu ; bi = b_ui
__global__ void pack_weights_kernel(
    const float* __restrict__ Wl_iu, const float* __restrict__ Wr_iu,
    const float* __restrict__ Wr_uu, const float* __restrict__ Wl_uu,
    const float* __restrict__ Wl_ui, const float* __restrict__ Wr_ui,
    const float* __restrict__ b_iu, const float* __restrict__ b_uu, const float* __restrict__ b_ui,
    unsigned short* __restrict__ Wu, unsigned short* __restrict__ Wi,
    float* __restrict__ bu, float* __restrict__ bi) {
  int id = blockIdx.x * 256 + threadIdx.x;
  const int NU = 128 * 384, NI = 128 * 256;
  if (id < NU) {
    int c = id / 384, k = id % 384;
    float v = (k < 128) ? Wl_iu[c * 128 + k]
            : (k < 256) ? (Wr_iu[c * 128 + k - 128] + Wr_uu[c * 128 + k - 128])
                        : Wl_uu[c * 128 + k - 256];
    Wu[id] = f2bf(v);
  } else if (id < NU + NI) {
    int j = id - NU;
    int c = j / 256, k = j % 256;
    float v = (k < 128) ? Wl_ui[c * 128 + k] : Wr_ui[c * 128 + k - 128];
    Wi[j] = f2bf(v);
  } else if (id < NU + NI + 256) {
    int j = id - NU - NI;
    if (j < 128) bu[j] = b_iu[j] + b_uu[j];
    else bi[j - 128] = b_ui[j - 128];
  }
}

// ---------------- mean aggregation (bf16 in / bf16 out): one wave per dst ----------------
__global__ __launch_bounds__(256) void aggregate_mean_bf16(
    unsigned short* __restrict__ mean, const unsigned short* __restrict__ xs,
    const int* __restrict__ srcs, const int* __restrict__ off, int Ndst) {
  int wid = threadIdx.x >> 6, lane = threadIdx.x & 63;
  int n = blockIdx.x * 4 + wid;
  if (n >= Ndst) return;
  int beg = off[n], end = off[n + 1];
  float sx = 0.f, sy = 0.f;
  int e = beg;
  for (; e + 3 < end; e += 4) {     // 4 independent gathers in flight
    unsigned v0 = *(const unsigned*)&xs[(size_t)srcs[e]     * C + lane * 2];
    unsigned v1 = *(const unsigned*)&xs[(size_t)srcs[e + 1] * C + lane * 2];
    unsigned v2 = *(const unsigned*)&xs[(size_t)srcs[e + 2] * C + lane * 2];
    unsigned v3 = *(const unsigned*)&xs[(size_t)srcs[e + 3] * C + lane * 2];
    sx += lo16f(v0) + lo16f(v1) + lo16f(v2) + lo16f(v3);
    sy += hi16f(v0) + hi16f(v1) + hi16f(v2) + hi16f(v3);
  }
  for (; e < end; e++) {
    unsigned v0 = *(const unsigned*)&xs[(size_t)srcs[e] * C + lane * 2];
    sx += lo16f(v0); sy += hi16f(v0);
  }
  float inv = 1.0f / fmaxf((float)(end - beg), 1.0f);
  unsigned outw = (unsigned)f2bf(sx * inv) | ((unsigned)f2bf(sy * inv) << 16);
  *(unsigned*)&mean[(size_t)n * C + lane * 2] = outw;
}

// ---------------- fused MFMA GEMM (+bias) + LayerNorm + ReLU ----------------
// Y[n][c] = sum_seg A_seg[n][:] . W[c][seg*128:...] ; then per-row LN, ReLU.
// Block = 256 thr = 4 waves; wave computes 16 rows x 128 cols (8 tiles of 16x16, K in 32-chunks).
// A layout: lane holds A[row=lane&15][k=(lane>>4)*8 + j]; B mirrored; C/D: col=lane&15, row=(lane>>4)*4+reg.
__global__ __launch_bounds__(256) void gemm_ln_relu(
    const unsigned short* A0, const unsigned short* A1, const unsigned short* A2, int nseg,
    const unsigned short* __restrict__ W, int Ktot,
    const float* __restrict__ bias, const float* __restrict__ lnw, const float* __restrict__ lnb,
    float* outf, unsigned short* outb, int N) {
  int lane = threadIdx.x & 63, wv = threadIdx.x >> 6;
  int n0 = blockIdx.x * 64 + wv * 16;
  int arow = lane & 15;
  int kq = (lane >> 4) * 8;
  f32x4 acc[8];
  #pragma unroll
  for (int t = 0; t < 8; t++) acc[t] = (f32x4){0.f, 0.f, 0.f, 0.f};
  const unsigned short* As[3] = { A0, A1, A2 };
  for (int s = 0; s < nseg; s++) {
    const unsigned short* Ap = As[s] + (size_t)(n0 + arow) * C + kq;   // rows padded to NP: in-bounds
    const unsigned short* Wp = W + (size_t)arow * Ktot + s * C + kq;
    #pragma unroll
    for (int kc = 0; kc < C; kc += 32) {
      short8 a = *(const short8*)(Ap + kc);
      #pragma unroll
      for (int t = 0; t < 8; t++) {
        short8 b = *(const short8*)(Wp + (size_t)(t * 16) * Ktot + kc);
        acc[t] = __builtin_amdgcn_mfma_f32_16x16x32_bf16(a, b, acc[t], 0, 0, 0);
      }
    }
  }
  // epilogue: + bias, LayerNorm over the 128 cols of each row, ReLU, store
  float lnwv[8], lnbv[8];
  #pragma unroll
  for (int t = 0; t < 8; t++) {
    int c = t * 16 + arow;
    float bv = bias[c];
    lnwv[t] = lnw[c]; lnbv[t] = lnb[c];
    #pragma unroll
    for (int r = 0; r < 4; r++) acc[t][r] += bv;
  }
  #pragma unroll
  for (int r = 0; r < 4; r++) {
    float s1 = 0.f, s2 = 0.f;
    #pragma unroll
    for (int t = 0; t < 8; t++) { float v = acc[t][r]; s1 += v; s2 += v * v; }
    #pragma unroll
    for (int d = 1; d < 16; d <<= 1) {   // reduce across the 16 lanes holding this row
      s1 += __shfl_xor(s1, d, 64);
      s2 += __shfl_xor(s2, d, 64);
    }
    float mu = s1 * (1.f / 128.f);
    float var = s2 * (1.f / 128.f) - mu * mu;
    float rs = rsqrtf(var + LN_EPS);
    int gr = n0 + (lane >> 4) * 4 + r;
    if (gr < N) {
      #pragma unroll
      for (int t = 0; t < 8; t++) {
        float y = (acc[t][r] - mu) * rs * lnwv[t] + lnbv[t];
        y = fmaxf(y, 0.f);
        int c = t * 16 + arow;
        if (outf) outf[(size_t)gr * C + c] = y;
        else      outb[(size_t)gr * C + c] = f2bf(y);
      }
    }
  }
}

extern "C" void kernel_launch(void* const* d_in, const int* in_sizes, int n_in,
                              void* d_out, int out_size, void* d_ws, size_t ws_size,
                              hipStream_t stream) {
  const float* xu = (const float*)d_in[0];
  const float* xi = (const float*)d_in[1];
  const int* ei[3] = { (const int*)d_in[2], (const int*)d_in[3], (const int*)d_in[4] };
  const float* P[26];
  for (int k = 0; k < 26; k++) P[k] = (const float*)d_in[5 + k];
  // per layer l, Q = P+13l: [0]Wl_ui [1]b_ui [2]Wr_ui [3]Wl_iu [4]b_iu [5]Wr_iu
  //                         [6]Wl_uu [7]b_uu [8]Wr_uu [9]lnw_u [10]lnb_u [11]lnw_i [12]lnb_i

  // ---- workspace (~73 MB) ----
  char* p = (char*)d_ws;
  auto alloc = [&](size_t bytes) { char* r = p; p += (bytes + 255) & ~(size_t)255; return r; };
  int *cnt[3], *off[3], *srcs[3];
  for (int t = 0; t < 3; t++) {
    cnt[t]  = (int*)alloc((size_t)NN * 4);
    off[t]  = (int*)alloc((size_t)(NN + 1) * 4);
    srcs[t] = (int*)alloc((size_t)NE * 4);
  }
  unsigned short* xb_u  = (unsigned short*)alloc((size_t)NP * C * 2);
  unsigned short* xb_i  = (unsigned short*)alloc((size_t)NP * C * 2);
  unsigned short* meanA = (unsigned short*)alloc((size_t)NP * C * 2);
  unsigned short* meanB = (unsigned short*)alloc((size_t)NP * C * 2);
  unsigned short* meanC = (unsigned short*)alloc((size_t)NP * C * 2);
  unsigned short *Wu[2], *Wi[2]; float *bu[2], *bi[2];
  for (int l = 0; l < 2; l++) {
    Wu[l] = (unsigned short*)alloc(128 * 384 * 2);
    Wi[l] = (unsigned short*)alloc(128 * 256 * 2);
    bu[l] = (float*)alloc(128 * 4);
    bi[l] = (float*)alloc(128 * 4);
  }

  // ---- CSR build (edges layer-invariant) ----
  const int EB = (NE + 255) / 256;
  for (int t = 0; t < 3; t++) hipMemsetAsync(cnt[t], 0, (size_t)NN * 4, stream);
  for (int t = 0; t < 3; t++)
    count_kernel<<<EB, 256, 0, stream>>>(cnt[t], ei[t] + NE, NE);
  scan3_kernel<<<3, 1024, 0, stream>>>(cnt[0], off[0], cnt[1], off[1], cnt[2], off[2], NN);
  for (int t = 0; t < 3; t++) hipMemsetAsync(cnt[t], 0, (size_t)NN * 4, stream);
  for (int t = 0; t < 3; t++)
    scatter_kernel<<<EB, 256, 0, stream>>>(srcs[t], cnt[t], ei[t], ei[t] + NE, off[t], NE);

  // ---- converts + weight packs ----
  const int n4 = NN * C / 4;
  f2bf4_kernel<<<(n4 + 255) / 256, 256, 0, stream>>>(xb_u, xu, n4);
  f2bf4_kernel<<<(n4 + 255) / 256, 256, 0, stream>>>(xb_i, xi, n4);
  const int PK = 128 * 384 + 128 * 256 + 256;
  for (int l = 0; l < 2; l++) {
    const float* const* Q = P + 13 * l;
    pack_weights_kernel<<<(PK + 255) / 256, 256, 0, stream>>>(
        Q[3], Q[5], Q[8], Q[6], Q[0], Q[2], Q[4], Q[7], Q[1],
        Wu[l], Wi[l], bu[l], bi[l]);
  }

  const int NBA = (NN + 3) / 4;
  const int NBG = NP / 64;   // 782

  for (int l = 0; l < 2; l++) {
    const float* const* Q = P + 13 * l;
    // aggregates first (they read xb_* which layer-l GEMMs overwrite in place)
    aggregate_mean_bf16<<<NBA, 256, 0, stream>>>(meanA, xb_u, srcs[0], off[0], NN);  // ui -> item side
    aggregate_mean_bf16<<<NBA, 256, 0, stream>>>(meanB, xb_i, srcs[1], off[1], NN);  // iu -> user side
    aggregate_mean_bf16<<<NBA, 256, 0, stream>>>(meanC, xb_u, srcs[2], off[2], NN);  // uu -> user side
    if (l == 0) {
      // in-place: each block reads only its own rows of A segments, then stores same rows
      gemm_ln_relu<<<NBG, 256, 0, stream>>>(meanA, xb_i, nullptr, 2, Wi[0], 256,
                                            bi[0], Q[11], Q[12], nullptr, xb_i, NN);
      gemm_ln_relu<<<NBG, 256, 0, stream>>>(meanB, xb_u, meanC, 3, Wu[0], 384,
                                            bu[0], Q[9], Q[10], nullptr, xb_u, NN);
    } else {
      float* out_u = (float*)d_out;
      float* out_i = (float*)d_out + (size_t)NN * C;
      gemm_ln_relu<<<NBG, 256, 0, stream>>>(meanA, xb_i, nullptr, 2, Wi[1], 256,
                                            bi[1], Q[11], Q[12], out_i, nullptr, NN);
      gemm_ln_relu<<<NBG, 256, 0, stream>>>(meanB, xb_u, meanC, 3, Wu[1], 384,
                                            bu[1], Q[9], Q[10], out_u, nullptr, NN);
    }
  }
  (void)in_sizes; (void)n_in; (void)out_size; (void)ws_size;
}

// Round 3
// 571.425 us; speedup vs baseline: 1.9978x; 1.3419x over previous
//
#include <hip/hip_runtime.h>

#define C 128
#define NN 50000     // N_USER == N_ITEM
#define NP 50048     // padded to multiple of 128 rows for GEMM tiles (391*128)
#define NE 600000
#define LN_EPS 1e-5f

typedef __attribute__((ext_vector_type(8))) short short8;
typedef __attribute__((ext_vector_type(4))) float f32x4;
typedef unsigned short u16;

union V16 { uint4 u; short8 s; };

__device__ inline float lo16f(unsigned v) { union { unsigned i; float f; } x; x.i = v << 16; return x.f; }
__device__ inline float hi16f(unsigned v) { union { unsigned i; float f; } x; x.i = v & 0xffff0000u; return x.f; }
__device__ inline u16 f2bf(float f) {
  union { float f; unsigned i; } x; x.f = f;
  unsigned r = (x.i + 0x7fffu + ((x.i >> 16) & 1u)) >> 16;   // RNE
  return (u16)r;
}

// ---------------- CSR build (all 3 edge types in one launch) ----------------
__global__ void count3_kernel(int* __restrict__ cntBase,
                              const int* d0, const int* d1, const int* d2) {
  int e = blockIdx.x * 256 + threadIdx.x;
  if (e >= 3 * NE) return;
  int t = e / NE, le = e - t * NE;
  const int* d = (t == 0) ? d0 : (t == 1) ? d1 : d2;
  atomicAdd(&cntBase[t * NN + d[le]], 1);
}

__global__ void scan3_kernel(const int* c0, int* o0, const int* c1, int* o1,
                             const int* c2, int* o2, int N) {
  const int* cnt = (blockIdx.x == 0) ? c0 : (blockIdx.x == 1) ? c1 : c2;
  int* off = (blockIdx.x == 0) ? o0 : (blockIdx.x == 1) ? o1 : o2;
  __shared__ int wsums[16];
  int tid = threadIdx.x, lane = tid & 63, wid = tid >> 6;
  if (tid == 0) off[0] = 0;
  int carry = 0;
  for (int base = 0; base < N; base += 1024) {
    int i = base + tid;
    int v = (i < N) ? cnt[i] : 0;
    int incl = v;
    #pragma unroll
    for (int d = 1; d < 64; d <<= 1) {
      int t = __shfl_up(incl, d, 64);
      if (lane >= d) incl += t;
    }
    if (lane == 63) wsums[wid] = incl;
    __syncthreads();
    if (wid == 0) {
      int w = (lane < 16) ? wsums[lane] : 0;
      #pragma unroll
      for (int d = 1; d < 16; d <<= 1) {
        int t = __shfl_up(w, d, 64);
        if (lane >= d) w += t;
      }
      if (lane < 16) wsums[lane] = w;
    }
    __syncthreads();
    int wave_prefix = (wid > 0) ? wsums[wid - 1] : 0;
    int total = wsums[15];
    if (i < N) off[i + 1] = carry + wave_prefix + incl;
    carry += total;
    __syncthreads();
  }
}

__global__ void scatter3_kernel(int* s0, int* s1, int* s2, int* __restrict__ fillBase,
                                const int* e0, const int* e1, const int* e2,
                                const int* o0, const int* o1, const int* o2) {
  int e = blockIdx.x * 256 + threadIdx.x;
  if (e >= 3 * NE) return;
  int t = e / NE, le = e - t * NE;
  const int* ei = (t == 0) ? e0 : (t == 1) ? e1 : e2;
  const int* off = (t == 0) ? o0 : (t == 1) ? o1 : o2;
  int* srcs = (t == 0) ? s0 : (t == 1) ? s1 : s2;
  int d = ei[NE + le];
  int pos = off[d] + atomicAdd(&fillBase[t * NN + d], 1);
  srcs[pos] = ei[le];
}

// ---------------- fp32 -> bf16 convert (both feature arrays, one launch) -------------
__global__ void f2bf_both_kernel(u16* __restrict__ du, const float* __restrict__ su,
                                 u16* __restrict__ di, const float* __restrict__ si, int n4) {
  int i = blockIdx.x * 256 + threadIdx.x;
  if (i >= 2 * n4) return;
  int second = i >= n4;
  int j = second ? i - n4 : i;
  float4 v = ((const float4*)(second ? si : su))[j];
  ushort4 o = make_ushort4(f2bf(v.x), f2bf(v.y), f2bf(v.z), f2bf(v.w));
  ((ushort4*)(second ? di : du))[j] = o;
}

// ---------------- weight pack: concat + bf16 (per layer) ----------------
// Wu[c][k]: k<128 -> Wl_iu; 128..255 -> Wr_iu+Wr_uu; 256..383 -> Wl_uu  (Ktot=384)
// Wi[c][k]: k<128 -> Wl_ui; 128..255 -> Wr_ui                           (Ktot=256)
__global__ void pack_weights_kernel(
    const float* __restrict__ Wl_iu, const float* __restrict__ Wr_iu,
    const float* __restrict__ Wr_uu, const float* __restrict__ Wl_uu,
    const float* __restrict__ Wl_ui, const float* __restrict__ Wr_ui,
    const float* __restrict__ b_iu, const float* __restrict__ b_uu, const float* __restrict__ b_ui,
    u16* __restrict__ Wu, u16* __restrict__ Wi,
    float* __restrict__ bu, float* __restrict__ bi) {
  int id = blockIdx.x * 256 + threadIdx.x;
  const int NU = 128 * 384, NI = 128 * 256;
  if (id < NU) {
    int c = id / 384, k = id % 384;
    float v = (k < 128) ? Wl_iu[c * 128 + k]
            : (k < 256) ? (Wr_iu[c * 128 + k - 128] + Wr_uu[c * 128 + k - 128])
                        : Wl_uu[c * 128 + k - 256];
    Wu[id] = f2bf(v);
  } else if (id < NU + NI) {
    int j = id - NU;
    int c = j / 256, k = j % 256;
    float v = (k < 128) ? Wl_ui[c * 128 + k] : Wr_ui[c * 128 + k - 128];
    Wi[j] = f2bf(v);
  } else if (id < NU + NI + 256) {
    int j = id - NU - NI;
    if (j < 128) bu[j] = b_iu[j] + b_uu[j];
    else bi[j - 128] = b_ui[j - 128];
  }
}

// ---------------- mean aggregation: quarter-wave per node, all 3 types ----------------
// 16 lanes own one node; each lane holds 8 channels (dwordx4 = 1KB gathered per wave instr).
__global__ __launch_bounds__(256) void aggregate3_kernel(
    u16* __restrict__ mA, u16* __restrict__ mB, u16* __restrict__ mC,
    const u16* __restrict__ xu, const u16* __restrict__ xi,
    const int* s0, const int* s1, const int* s2,
    const int* o0, const int* o1, const int* o2) {
  int lane = threadIdx.x & 63, wv = threadIdx.x >> 6;
  int q = lane >> 4, ql = lane & 15;
  int nid = blockIdx.x * 16 + wv * 4 + q;
  if (nid >= 3 * NN) return;
  int t = (nid >= 2 * NN) ? 2 : (nid >= NN) ? 1 : 0;
  int n = nid - t * NN;
  const int* off  = (t == 0) ? o0 : (t == 1) ? o1 : o2;
  const int* srcs = (t == 0) ? s0 : (t == 1) ? s1 : s2;
  const u16* xs   = (t == 1) ? xi : xu;
  u16* mean       = (t == 0) ? mA : (t == 1) ? mB : mC;
  int beg = off[n], end = off[n + 1];
  float s[8] = {0.f, 0.f, 0.f, 0.f, 0.f, 0.f, 0.f, 0.f};
  int e = beg;
  for (; e + 1 < end; e += 2) {
    int i0 = srcs[e], i1 = srcs[e + 1];
    uint4 v0 = *(const uint4*)(xs + (size_t)i0 * C + ql * 8);
    uint4 v1 = *(const uint4*)(xs + (size_t)i1 * C + ql * 8);
    s[0] += lo16f(v0.x) + lo16f(v1.x); s[1] += hi16f(v0.x) + hi16f(v1.x);
    s[2] += lo16f(v0.y) + lo16f(v1.y); s[3] += hi16f(v0.y) + hi16f(v1.y);
    s[4] += lo16f(v0.z) + lo16f(v1.z); s[5] += hi16f(v0.z) + hi16f(v1.z);
    s[6] += lo16f(v0.w) + lo16f(v1.w); s[7] += hi16f(v0.w) + hi16f(v1.w);
  }
  if (e < end) {
    uint4 v0 = *(const uint4*)(xs + (size_t)srcs[e] * C + ql * 8);
    s[0] += lo16f(v0.x); s[1] += hi16f(v0.x);
    s[2] += lo16f(v0.y); s[3] += hi16f(v0.y);
    s[4] += lo16f(v0.z); s[5] += hi16f(v0.z);
    s[6] += lo16f(v0.w); s[7] += hi16f(v0.w);
  }
  float inv = 1.0f / fmaxf((float)(end - beg), 1.0f);
  uint4 o;
  o.x = (unsigned)f2bf(s[0] * inv) | ((unsigned)f2bf(s[1] * inv) << 16);
  o.y = (unsigned)f2bf(s[2] * inv) | ((unsigned)f2bf(s[3] * inv) << 16);
  o.z = (unsigned)f2bf(s[4] * inv) | ((unsigned)f2bf(s[5] * inv) << 16);
  o.w = (unsigned)f2bf(s[6] * inv) | ((unsigned)f2bf(s[7] * inv) << 16);
  *(uint4*)(mean + (size_t)n * C + ql * 8) = o;
}

// ---------------- fused MFMA GEMM (+bias) + LayerNorm + ReLU, W staged in LDS --------
// BM=128 rows/block (4 waves x 32 rows), BN=128 (full C), K looped in 128-segments.
// W seg staged in LDS padded to 136 u16/row (272B stride -> 2-way bank alias = free).
// Fragments: A lane=A[row=lane&15][k=(lane>>4)*8+j]; B lane=W[col=t*16+(lane&15)][k]; 
// C/D: col=lane&15, row=(lane>>4)*4+reg.
__global__ __launch_bounds__(256) void gemm_ln_relu(
    const u16* A0, const u16* A1, const u16* A2, int nseg,
    const u16* __restrict__ W, int Ktot,
    const float* __restrict__ bias, const float* __restrict__ lnw, const float* __restrict__ lnb,
    float* outf, u16* outb, int N) {
  __shared__ u16 Wt[128][136];
  int tid = threadIdx.x, lane = tid & 63, wv = tid >> 6;
  int arow = lane & 15, kq = (lane >> 4) * 8;
  int n0 = blockIdx.x * 128 + wv * 32;
  f32x4 acc[2][8];
  #pragma unroll
  for (int g = 0; g < 2; g++)
    #pragma unroll
    for (int t = 0; t < 8; t++) acc[g][t] = (f32x4){0.f, 0.f, 0.f, 0.f};
  const u16* As[3] = { A0, A1, A2 };

  for (int sg = 0; sg < nseg; sg++) {
    __syncthreads();
    #pragma unroll
    for (int it = 0; it < 8; it++) {            // stage 128x128 W segment (32 KB)
      int chunk = it * 256 + tid;               // 2048 chunks of 8 bf16
      int c = chunk >> 4;
      int k8 = (chunk & 15) * 8;
      uint4 v = *(const uint4*)(W + (size_t)c * Ktot + sg * 128 + k8);
      *(uint4*)&Wt[c][k8] = v;
    }
    __syncthreads();
    const u16* Ar0 = As[sg] + (size_t)(n0 + arow) * C + kq;
    const u16* Ar1 = As[sg] + (size_t)(n0 + 16 + arow) * C + kq;
    V16 a0[4], a1[4];
    #pragma unroll
    for (int c4 = 0; c4 < 4; c4++) {
      a0[c4].u = *(const uint4*)(Ar0 + c4 * 32);
      a1[c4].u = *(const uint4*)(Ar1 + c4 * 32);
    }
    #pragma unroll
    for (int c4 = 0; c4 < 4; c4++) {
      #pragma unroll
      for (int t = 0; t < 8; t++) {
        short8 b = *(const short8*)&Wt[t * 16 + arow][kq + c4 * 32];
        acc[0][t] = __builtin_amdgcn_mfma_f32_16x16x32_bf16(a0[c4].s, b, acc[0][t], 0, 0, 0);
        acc[1][t] = __builtin_amdgcn_mfma_f32_16x16x32_bf16(a1[c4].s, b, acc[1][t], 0, 0, 0);
      }
    }
  }
  // epilogue: bias + per-row LayerNorm + ReLU
  float bv[8], lnwv[8], lnbv[8];
  #pragma unroll
  for (int t = 0; t < 8; t++) {
    int c = t * 16 + arow;
    bv[t] = bias[c]; lnwv[t] = lnw[c]; lnbv[t] = lnb[c];
  }
  #pragma unroll
  for (int g = 0; g < 2; g++) {
    #pragma unroll
    for (int r = 0; r < 4; r++) {
      float s1 = 0.f, s2 = 0.f;
      #pragma unroll
      for (int t = 0; t < 8; t++) {
        float v = acc[g][t][r] + bv[t];
        s1 += v; s2 += v * v;
      }
      #pragma unroll
      for (int d = 1; d < 16; d <<= 1) {
        s1 += __shfl_xor(s1, d, 64);
        s2 += __shfl_xor(s2, d, 64);
      }
      float mu = s1 * (1.f / 128.f);
      float var = s2 * (1.f / 128.f) - mu * mu;
      float rs = rsqrtf(var + LN_EPS);
      int gr = n0 + g * 16 + (lane >> 4) * 4 + r;
      if (gr < N) {
        #pragma unroll
        for (int t = 0; t < 8; t++) {
          float y = (acc[g][t][r] + bv[t] - mu) * rs * lnwv[t] + lnbv[t];
          y = fmaxf(y, 0.f);
          int c = t * 16 + arow;
          if (outf) outf[(size_t)gr * C + c] = y;
          else      outb[(size_t)gr * C + c] = f2bf(y);
        }
      }
    }
  }
}

extern "C" void kernel_launch(void* const* d_in, const int* in_sizes, int n_in,
                              void* d_out, int out_size, void* d_ws, size_t ws_size,
                              hipStream_t stream) {
  const float* xu = (const float*)d_in[0];
  const float* xi = (const float*)d_in[1];
  const int* ei[3] = { (const int*)d_in[2], (const int*)d_in[3], (const int*)d_in[4] };
  const float* P[26];
  for (int k = 0; k < 26; k++) P[k] = (const float*)d_in[5 + k];
  // per layer l, Q = P+13l: [0]Wl_ui [1]b_ui [2]Wr_ui [3]Wl_iu [4]b_iu [5]Wr_iu
  //                         [6]Wl_uu [7]b_uu [8]Wr_uu [9]lnw_u [10]lnb_u [11]lnw_i [12]lnb_i

  // ---- workspace ----
  char* p = (char*)d_ws;
  auto alloc = [&](size_t bytes) { char* r = p; p += (bytes + 255) & ~(size_t)255; return r; };
  int* cntBase = (int*)alloc((size_t)3 * NN * 4);   // 3 contiguous count/fill arrays
  int *off[3], *srcs[3];
  for (int t = 0; t < 3; t++) {
    off[t]  = (int*)alloc((size_t)(NN + 1) * 4);
    srcs[t] = (int*)alloc((size_t)NE * 4);
  }
  u16* xb_u  = (u16*)alloc((size_t)NP * C * 2);
  u16* xb_i  = (u16*)alloc((size_t)NP * C * 2);
  u16* meanA = (u16*)alloc((size_t)NP * C * 2);
  u16* meanB = (u16*)alloc((size_t)NP * C * 2);
  u16* meanC = (u16*)alloc((size_t)NP * C * 2);
  u16 *Wu[2], *Wi[2]; float *bu[2], *bi[2];
  for (int l = 0; l < 2; l++) {
    Wu[l] = (u16*)alloc(128 * 384 * 2);
    Wi[l] = (u16*)alloc(128 * 256 * 2);
    bu[l] = (float*)alloc(128 * 4);
    bi[l] = (float*)alloc(128 * 4);
  }

  // ---- CSR build ----
  const int EB3 = (3 * NE + 255) / 256;
  hipMemsetAsync(cntBase, 0, (size_t)3 * NN * 4, stream);
  count3_kernel<<<EB3, 256, 0, stream>>>(cntBase, ei[0] + NE, ei[1] + NE, ei[2] + NE);
  scan3_kernel<<<3, 1024, 0, stream>>>(cntBase, off[0], cntBase + NN, off[1], cntBase + 2 * NN, off[2], NN);
  hipMemsetAsync(cntBase, 0, (size_t)3 * NN * 4, stream);
  scatter3_kernel<<<EB3, 256, 0, stream>>>(srcs[0], srcs[1], srcs[2], cntBase,
                                           ei[0], ei[1], ei[2], off[0], off[1], off[2]);

  // ---- converts + weight packs ----
  const int n4 = NN * C / 4;
  f2bf_both_kernel<<<(2 * n4 + 255) / 256, 256, 0, stream>>>(xb_u, xu, xb_i, xi, n4);
  const int PK = 128 * 384 + 128 * 256 + 256;
  for (int l = 0; l < 2; l++) {
    const float* const* Q = P + 13 * l;
    pack_weights_kernel<<<(PK + 255) / 256, 256, 0, stream>>>(
        Q[3], Q[5], Q[8], Q[6], Q[0], Q[2], Q[4], Q[7], Q[1],
        Wu[l], Wi[l], bu[l], bi[l]);
  }

  const int NBA = (3 * NN + 15) / 16;   // 9375
  const int NBG = NP / 128;             // 391

  for (int l = 0; l < 2; l++) {
    const float* const* Q = P + 13 * l;
    aggregate3_kernel<<<NBA, 256, 0, stream>>>(meanA, meanB, meanC, xb_u, xb_i,
                                               srcs[0], srcs[1], srcs[2],
                                               off[0], off[1], off[2]);
    if (l == 0) {
      gemm_ln_relu<<<NBG, 256, 0, stream>>>(meanA, xb_i, nullptr, 2, Wi[0], 256,
                                            bi[0], Q[11], Q[12], nullptr, xb_i, NN);
      gemm_ln_relu<<<NBG, 256, 0, stream>>>(meanB, xb_u, meanC, 3, Wu[0], 384,
                                            bu[0], Q[9], Q[10], nullptr, xb_u, NN);
    } else {
      float* out_u = (float*)d_out;
      float* out_i = (float*)d_out + (size_t)NN * C;
      gemm_ln_relu<<<NBG, 256, 0, stream>>>(meanA, xb_i, nullptr, 2, Wi[1], 256,
                                            bi[1], Q[11], Q[12], out_i, nullptr, NN);
      gemm_ln_relu<<<NBG, 256, 0, stream>>>(meanB, xb_u, meanC, 3, Wu[1], 384,
                                            bu[1], Q[9], Q[10], out_u, nullptr, NN);
    }
  }
  (void)in_sizes; (void)n_in; (void)out_size; (void)ws_size;
}